// Round 14
// baseline (1699.280 us; speedup 1.0000x reference)
//
#include <hip/hip_runtime.h>
#include <hip/hip_bf16.h>
#include <cstdint>

#define DI __device__ __forceinline__

typedef unsigned short ushort_t;
using u16x8  = __attribute__((ext_vector_type(8))) unsigned short;
using bf16x8 = __attribute__((ext_vector_type(8))) __bf16;
using f32x4  = __attribute__((ext_vector_type(4))) float;

typedef const __attribute__((address_space(1))) void GVOID;
typedef __attribute__((address_space(3))) void LVOID;

enum { BB = 16384, DIN = 512, H0 = 1024, H1 = 1024, DOUT = 64, NE = 8, GH = 128 };

DI void async_ld16(const void* g, void* l) {
    __builtin_amdgcn_global_load_lds((GVOID*)g, (LVOID*)l, 16, 0, 0);
}

DI unsigned short f2bf(float f) {  // RTNE f32 -> bf16 bits
    union { float f; unsigned u; } v; v.f = f;
    unsigned r = v.u + 0x7FFF + ((v.u >> 16) & 1);
    return (unsigned short)(r >> 16);
}
DI float bf2f(unsigned short u) { return __uint_as_float(((unsigned)u) << 16); }
DI f32x4 zero4() { f32x4 v = {0.f, 0.f, 0.f, 0.f}; return v; }

// ---------------------------------------------------------------------------
// f32 -> bf16 convert (inputs), 8 elems/thread, exact grid
// ---------------------------------------------------------------------------
__global__ void f32_to_bf16_vec(const float* __restrict__ in, ushort_t* __restrict__ out) {
    const int i = (blockIdx.x * 256 + threadIdx.x) * 8;
    const float4 a = *(const float4*)&in[i];
    const float4 b = *(const float4*)&in[i + 4];
    u16x8 o;
    o[0] = f2bf(a.x); o[1] = f2bf(a.y); o[2] = f2bf(a.z); o[3] = f2bf(a.w);
    o[4] = f2bf(b.x); o[5] = f2bf(b.y); o[6] = f2bf(b.z); o[7] = f2bf(b.w);
    *(u16x8*)&out[i] = o;
}

// ---------------------------------------------------------------------------
// W [K][N] f32 -> Wt [N][Kext] bf16 (cols [0,K)), 64x64 tiles via LDS
// ---------------------------------------------------------------------------
__global__ void transpose_convert(const float* __restrict__ W, ushort_t* __restrict__ Wt,
                                  int K, int N, int Kext) {
    __shared__ float t[64][69];
    const int tid = threadIdx.x;
    const int k0 = blockIdx.x * 64, n0 = blockIdx.y * 64;
    for (int rr = tid >> 4; rr < 64; rr += 16) {
        const int c = (tid & 15) * 4;
        const float4 v = *(const float4*)&W[(size_t)(k0 + rr) * N + n0 + c];
        t[rr][c] = v.x; t[rr][c + 1] = v.y; t[rr][c + 2] = v.z; t[rr][c + 3] = v.w;
    }
    __syncthreads();
    for (int nn = tid >> 3; nn < 64; nn += 32) {
        const int k8 = (tid & 7) * 8;
        u16x8 o;
#pragma unroll
        for (int j = 0; j < 8; ++j) o[j] = f2bf(t[k8 + j][nn]);
        *(u16x8*)&Wt[(size_t)(n0 + nn) * Kext + k0 + k8] = o;
    }
}

// ---------------------------------------------------------------------------
// Fill appended bias chunk: Wt[n][K + c] = bias[c][n] for c<8, else 0
// ---------------------------------------------------------------------------
__global__ void bias_fill(const float* __restrict__ bias, ushort_t* __restrict__ Wt,
                          int N, int K, int Kext) {
    const int n = blockIdx.x, c = threadIdx.x;  // 128 threads
    Wt[(size_t)n * Kext + K + c] = (c < 8) ? f2bf(bias[(size_t)c * N + n]) : (ushort_t)0;
}

// ---------------------------------------------------------------------------
// gate layer 3 + softmax: h2 [B,128] bf16 @ gw3 [128,8] f32 + gb3 -> softmax
// writes g [B,8] f32  AND  Gx [B,128] bf16 = (g | zeros)
// ---------------------------------------------------------------------------
__global__ void gate3_softmax(const ushort_t* __restrict__ h2, const float* __restrict__ gw3,
                              const float* __restrict__ gb3, float* __restrict__ g,
                              ushort_t* __restrict__ Gx) {
    __shared__ float w[GH * NE];
    const int tid = threadIdx.x;
    for (int i = tid; i < GH * NE; i += 256) w[i] = gw3[i];
    __syncthreads();
    const int b = blockIdx.x * 256 + tid;
    float lg[NE];
#pragma unroll
    for (int e = 0; e < NE; ++e) lg[e] = gb3[e];
    const ushort_t* row = h2 + (size_t)b * GH;
    for (int h8 = 0; h8 < GH; h8 += 8) {
        const u16x8 v = *(const u16x8*)&row[h8];
#pragma unroll
        for (int j = 0; j < 8; ++j) {
            const float xv = bf2f(v[j]);
#pragma unroll
            for (int e = 0; e < NE; ++e) lg[e] += xv * w[(h8 + j) * NE + e];
        }
    }
    float mx = lg[0];
#pragma unroll
    for (int e = 1; e < NE; ++e) mx = fmaxf(mx, lg[e]);
    float s = 0.f;
#pragma unroll
    for (int e = 0; e < NE; ++e) { lg[e] = __expf(lg[e] - mx); s += lg[e]; }
    const float inv = 1.f / s;
#pragma unroll
    for (int e = 0; e < NE; ++e) g[(size_t)b * NE + e] = lg[e] * inv;
    ushort_t* gxr = Gx + (size_t)b * 128;
    u16x8 o;
#pragma unroll
    for (int e = 0; e < NE; ++e) o[e] = f2bf(lg[e] * inv);
    *(u16x8*)gxr = o;
    u16x8 z = {0, 0, 0, 0, 0, 0, 0, 0};
#pragma unroll
    for (int i = 1; i < 16; ++i) *(u16x8*)(gxr + i * 8) = z;
}

// ---------------------------------------------------------------------------
// A-IN-REGISTERS MoE GEMM (128x128 tile).  out = relu(sum_e g_e(X W_e) + ...)
// Model (r5-r13): barrier-aligned 256^2 family serializes MFMA (2483cy/tile)
// with 192KB/tile LDS reads (~2000cy) -> 47% plateau. Fix: cut LDS traffic.
//  - B (weights) staged in LDS: 16 KB/tile, 2-buf; per-wave reads only 4
//    ds_read_b128/tile (12x less LDS traffic than the 256^2 kernel).
//  - A loaded per-wave DIRECTLY global->VGPR: global_load_dwordx4 of
//    X[(bm0+m*16+lr)*STRIDE + kcol + lk*8] IS the bf16x8 MFMA A-fragment.
//    A amplification (4 waves x 8 N-blocks = 32x) is L2-absorbed: XCD decode
//    puts all 8 N-blocks of one A-panel (2.1 MB < 4 MB L2) on one XCD.
//  - One __syncthreads per tile (m97-simple); compiler emits counted waits
//    for A-frag uses; stB(t+1) issued right after the tile-opening barrier
//    lands ~1 full tile (~1500cy) before its consumption barrier.
// 256 threads = 4 waves (1M x 4N); per-wave 128 rows x 32 cols, acc[8][2].
// VGPR: acc 64 + A-frags (scheduler-managed) + B 32 + addr; bounds <=256.
// LDS: 2x16KB B + 4KB rtab = 36 KB -> >=2 blocks/CU (8 waves) for TLP.
// Horner gate fold at expert boundaries; bias folded as appended K-chunk.
// ---------------------------------------------------------------------------
template <int TPE64, int STRIDEX>
__global__ __launch_bounds__(256, 2) void gemm_areg(
    const ushort_t* __restrict__ X,     // [M, STRIDEX] bf16
    const ushort_t* __restrict__ Gx,    // [M, 128] bf16
    const ushort_t* __restrict__ Wt,    // [N, Kext] bf16
    const float* __restrict__ gvec,     // [M, 8] f32
    ushort_t* __restrict__ out,         // [M, N] bf16
    int N, int Kext) {
    constexpr int TE64 = NE * TPE64;    // # expert K-tiles (of 64)
    const int NT = Kext >> 6;           // total K-tiles
    const int tid = threadIdx.x;
    const int wid = tid >> 6, l = tid & 63;
    const int wn = wid;                 // 4 waves across N (32 cols each)
    const int lr = l & 15, lk = l >> 4;

    // XCD decode: the 8 N-blocks sharing an A-panel co-reside on one XCD.
    // b = xcd + 8*by + 64*hi  (1024 = 8 xcd x 8 by x 16 hi), bx = xcd + 8*hi.
    const int b = blockIdx.x;
    const int xcd = b & 7;
    const int by = (b >> 3) & 7;
    const int bx = xcd + 8 * (b >> 6);
    const int bm0 = bx * 128, bn0 = by * 128;

    __shared__ __align__(1024) char lB[2][16384];  // [dbuf][128 n-rows x 64 k]
    __shared__ float rtab[128 * 8];                // Horner ratios (4 KB)

    // ratio table: r[row][e] = g_e/g_{e+1} (e<7), r[row][7] = g_7
    if (tid < 128) {
        const float* gr = gvec + (size_t)(bm0 + tid) * 8;
        float ge[8];
#pragma unroll
        for (int e = 0; e < 8; ++e) ge[e] = gr[e];
#pragma unroll
        for (int e = 0; e < 7; ++e) rtab[tid * 8 + e] = ge[e] / ge[e + 1];
        rtab[tid * 8 + 7] = ge[7];
    }

    // ---- B staging: 16 KB/tile = 4 gload_lds/thread; dst linear (wave base
    // + lane*16 implicit), src pre-swizzled: LDS slot (row, c) holds global
    // 16B-chunk c ^ (row&7).  row = r*32 + wid*8 + (l>>3)  (row&7 = (l>>3)&7)
    auto stB = [&](int t, int buf) {
#pragma unroll
        for (int r = 0; r < 4; ++r) {
            char* dst = (char*)lB[buf] + r * 4096 + (wid << 10);
            const int row = r * 32 + wid * 8 + (l >> 3);
            const int col = t * 64 + (((l & 7) ^ ((l >> 3) & 7)) << 3);
            async_ld16(Wt + (size_t)(bn0 + row) * Kext + col, dst);
        }
    };

    // B-frag LDS read addressing: frag (n, k2): row = wn*32 + n*16 + lr,
    // chunk = (k2*4 + lk) ^ (lr&7)  ->  byte = row*128 + chunk*16.
    const int bc0 = ((lk ^ (lr & 7)) << 4);          // k2=0; k2=1 -> ^64
    const int boff = (wn * 32 + lr) * 128;           // + n*2048 + chunk

    // A global fragment base: lane-private row lr, k-group lk.
    const ushort_t* aX = X + (size_t)(bm0 + lr) * STRIDEX + lk * 8;
    const ushort_t* aG = Gx + (size_t)(bm0 + lr) * 128 + lk * 8;

    f32x4 acc[8][2];
#pragma unroll
    for (int m = 0; m < 8; ++m) { acc[m][0] = zero4(); acc[m][1] = zero4(); }

    stB(0, 0);
    __syncthreads();  // B(0) resident; rtab visible

    int buf = 0;
    for (int t = 0; t < NT; ++t) {
        if (t + 1 < NT) stB(t + 1, buf ^ 1);  // lands before next barrier

        const char* Bp = lB[buf];
        bf16x8 b00, b01, b10, b11;
        b00 = *(const bf16x8*)(Bp + boff + bc0);
        b01 = *(const bf16x8*)(Bp + boff + (bc0 ^ 64));
        b10 = *(const bf16x8*)(Bp + boff + 2048 + bc0);
        b11 = *(const bf16x8*)(Bp + boff + 2048 + (bc0 ^ 64));

        // A fragments straight from global (L2-hot panel), unrolled m-loop
        if (t < TE64) {
            const ushort_t* ap = aX + (t & (TPE64 - 1)) * 64;
#pragma unroll
            for (int m = 0; m < 8; ++m) {
                const bf16x8 a0 = *(const bf16x8*)(ap + (size_t)(m * 16) * STRIDEX);
                const bf16x8 a1 = *(const bf16x8*)(ap + (size_t)(m * 16) * STRIDEX + 32);
                acc[m][0] = __builtin_amdgcn_mfma_f32_16x16x32_bf16(a0, b00, acc[m][0], 0, 0, 0);
                acc[m][0] = __builtin_amdgcn_mfma_f32_16x16x32_bf16(a1, b01, acc[m][0], 0, 0, 0);
                acc[m][1] = __builtin_amdgcn_mfma_f32_16x16x32_bf16(a0, b10, acc[m][1], 0, 0, 0);
                acc[m][1] = __builtin_amdgcn_mfma_f32_16x16x32_bf16(a1, b11, acc[m][1], 0, 0, 0);
            }
        } else {
            const ushort_t* ap = aG + (t - TE64) * 64;
#pragma unroll
            for (int m = 0; m < 8; ++m) {
                const bf16x8 a0 = *(const bf16x8*)(ap + (size_t)(m * 16) * 128);
                const bf16x8 a1 = *(const bf16x8*)(ap + (size_t)(m * 16) * 128 + 32);
                acc[m][0] = __builtin_amdgcn_mfma_f32_16x16x32_bf16(a0, b00, acc[m][0], 0, 0, 0);
                acc[m][0] = __builtin_amdgcn_mfma_f32_16x16x32_bf16(a1, b01, acc[m][0], 0, 0, 0);
                acc[m][1] = __builtin_amdgcn_mfma_f32_16x16x32_bf16(a0, b10, acc[m][1], 0, 0, 0);
                acc[m][1] = __builtin_amdgcn_mfma_f32_16x16x32_bf16(a1, b11, acc[m][1], 0, 0, 0);
            }
        }

        // Horner gate fold at expert boundary (register-only + rtab reads)
        if (t < TE64 && ((t + 1) & (TPE64 - 1)) == 0) {
            const int e = t / TPE64;
#pragma unroll
            for (int m = 0; m < 8; ++m)
#pragma unroll
                for (int q = 0; q < 4; ++q) {
                    const float r = rtab[(m * 16 + lk * 4 + q) * 8 + e];
                    acc[m][0][q] *= r;
                    acc[m][1][q] *= r;
                }
        }

        buf ^= 1;
        __syncthreads();  // drains vmcnt (B(t+1) + A stragglers); opens t+1
    }

    // ---- epilogue: relu + bf16 store (bias already folded via K-chunk) ----
#pragma unroll
    for (int m = 0; m < 8; ++m) {
        const int row = bm0 + m * 16 + lk * 4;
#pragma unroll
        for (int n = 0; n < 2; ++n) {
            const int col = bn0 + wn * 32 + n * 16 + lr;
#pragma unroll
            for (int q = 0; q < 4; ++q) {
                const float v = fmaxf(acc[m][n][q], 0.f);
                out[(size_t)(row + q) * N + col] = f2bf(v);
            }
        }
    }
}

// ---------------------------------------------------------------------------
// Legacy fused (MoE-)GEMM — gate MLP (ungated, BN=64 for 2x grid) and final
// L2 layer (per-expert split-K). ACT: 0=relu, 1=tanh, 2=none (raw partial).
// TPE>0 with GATED=false: TPE only sets the A-stride (xstride = TPE*BK).
// ---------------------------------------------------------------------------
template <int BN, int TPE, int ACT, bool GATED, bool OUTF32>
__global__ __launch_bounds__(256, 2) void moe_gemm(
    const ushort_t* __restrict__ X, const ushort_t* __restrict__ Wt,
    const float* __restrict__ gvec, const float* __restrict__ bias,
    void* __restrict__ outv, int M, int N, int K, int Klen) {
    constexpr int BM = 128, BK = 64;
    constexpr int NF = BN / 32;
    const int tid = threadIdx.x;
    const int wid = tid >> 6, lane = tid & 63;
    const int lr = lane & 15, lk = lane >> 4;
    const int bm0 = blockIdx.x * BM;
    const int bn0 = blockIdx.y * BN;
    const int wm0 = (wid >> 1) * 64;
    const int wn0 = (wid & 1) * (BN / 2);
    const int koff = blockIdx.z * Klen;
    const int te0 = (TPE > 0) ? koff / (TPE * BK) : 0;

    __shared__ short lds_a[BM * BK];
    __shared__ short lds_b[BN * BK];
    __shared__ float lds_g[BM * 8];
    __shared__ float lds_bias[8 * BN];

    if constexpr (GATED) {
        ((f32x4*)lds_g)[tid] = ((const f32x4*)(gvec + (size_t)bm0 * 8))[tid];
        if constexpr (ACT != 2) {
            for (int i = tid; i < 8 * BN; i += 256) {
                const int e = i / BN, n = i - e * BN;
                lds_bias[i] = bias[(size_t)e * N + bn0 + n];
            }
        }
    }

    f32x4 acc_t[4][NF], acc_p[4][NF];
#pragma unroll
    for (int m = 0; m < 4; ++m)
#pragma unroll
        for (int n = 0; n < NF; ++n) { acc_t[m][n] = zero4(); acc_p[m][n] = zero4(); }

    f32x4(&amain)[4][NF] = GATED ? acc_p : acc_t;

    const int xstride = (TPE > 0) ? TPE * BK : K;
    const int NT = Klen / BK;
    for (int kt = 0; kt < NT; ++kt) {
        int kcolA;
        if constexpr (TPE > 0) kcolA = (kt % TPE) * BK; else kcolA = kt * BK;
        {
            const ushort_t* abase = X + (size_t)bm0 * xstride + kcolA;
#pragma unroll
            for (int c = wid; c < (BM * BK * 2) / 1024; c += 4) {
                const int off = c * 1024 + lane * 16;
                const int r = off >> 7, cbyte = off & 127;
                async_ld16((const char*)abase + (size_t)r * (xstride * 2) + cbyte,
                           (char*)lds_a + c * 1024);
            }
            const ushort_t* bbase = Wt + (size_t)bn0 * K + koff + kt * BK;
#pragma unroll
            for (int c = wid; c < (BN * BK * 2) / 1024; c += 4) {
                const int off = c * 1024 + lane * 16;
                const int r = off >> 7, cbyte = off & 127;
                async_ld16((const char*)bbase + (size_t)r * ((size_t)K * 2) + cbyte,
                           (char*)lds_b + c * 1024);
            }
        }
        __syncthreads();

        bf16x8 af[2][4], bfr[2][NF];
#pragma unroll
        for (int k2 = 0; k2 < 2; ++k2) {
#pragma unroll
            for (int m = 0; m < 4; ++m)
                af[k2][m] = *(const bf16x8*)&lds_a[(wm0 + m * 16 + lr) * BK + k2 * 32 + lk * 8];
#pragma unroll
            for (int n = 0; n < NF; ++n)
                bfr[k2][n] = *(const bf16x8*)&lds_b[(wn0 + n * 16 + lr) * BK + k2 * 32 + lk * 8];
        }
#pragma unroll
        for (int m = 0; m < 4; ++m)
#pragma unroll
            for (int n = 0; n < NF; ++n) {
                amain[m][n] = __builtin_amdgcn_mfma_f32_16x16x32_bf16(af[0][m], bfr[0][n], amain[m][n], 0, 0, 0);
                amain[m][n] = __builtin_amdgcn_mfma_f32_16x16x32_bf16(af[1][m], bfr[1][n], amain[m][n], 0, 0, 0);
            }

        if constexpr (TPE > 0 && GATED) {
            if ((kt + 1) % TPE == 0) {
                const int e = te0 + kt / TPE;
#pragma unroll
                for (int m = 0; m < 4; ++m)
#pragma unroll
                    for (int q = 0; q < 4; ++q) {
                        const float gw = lds_g[(wm0 + m * 16 + lk * 4 + q) * 8 + e];
#pragma unroll
                        for (int n = 0; n < NF; ++n) {
                            acc_t[m][n][q] += gw * acc_p[m][n][q];
                            acc_p[m][n][q] = 0.f;
                        }
                    }
            }
        }
        __syncthreads();
    }

#pragma unroll
    for (int m = 0; m < 4; ++m)
#pragma unroll
        for (int n = 0; n < NF; ++n)
#pragma unroll
            for (int q = 0; q < 4; ++q) {
                const int row = wm0 + m * 16 + lk * 4 + q;
                const int col = wn0 + n * 16 + lr;
                float v = acc_t[m][n][q];
                if constexpr (ACT != 2) {
                    if constexpr (GATED) {
                        float bs = 0.f;
#pragma unroll
                        for (int e = 0; e < 8; ++e) bs += lds_g[row * 8 + e] * lds_bias[e * BN + col];
                        v += bs;
                    } else {
                        v += bias[bn0 + col];
                    }
                }
                if constexpr (ACT == 0) v = fmaxf(v, 0.f);
                else if constexpr (ACT == 1) v = tanhf(v);
                const size_t oidx = (size_t)blockIdx.z * M * N + (size_t)(bm0 + row) * N + (bn0 + col);
                if constexpr (OUTF32) ((float*)outv)[oidx] = v;
                else ((ushort_t*)outv)[oidx] = f2bf(v);
            }
}

// ---------------------------------------------------------------------------
// per-expert split-K reduce for L2: out[i] = tanh(sum_e g_e*(part_e[i]+b2_e))
// part layout: [8][B][64] f32
// ---------------------------------------------------------------------------
__global__ void splitk_reduce8(const float* __restrict__ part, const float* __restrict__ g,
                               const float* __restrict__ b2, float* __restrict__ out) {
    __shared__ float bs[8 * 64];
    const int tid = threadIdx.x;
    for (int i = tid; i < 512; i += 256) bs[i] = b2[i];
    __syncthreads();
    const int idx = blockIdx.x * 256 + tid;
    const int bb = idx >> 6, n = idx & 63;
    const float* gr = g + (size_t)bb * 8;
    float v = 0.f;
#pragma unroll
    for (int e = 0; e < 8; ++e)
        v += gr[e] * (part[(size_t)e * BB * 64 + idx] + bs[e * 64 + n]);
    out[idx] = tanhf(v);
}

// ---------------------------------------------------------------------------
extern "C" void kernel_launch(void* const* d_in, const int* in_sizes, int n_in,
                              void* d_out, int out_size, void* d_ws, size_t ws_size,
                              hipStream_t stream) {
    const float* inputs = (const float*)d_in[0];
    const float* gw1 = (const float*)d_in[1];
    const float* gb1 = (const float*)d_in[2];
    const float* gw2 = (const float*)d_in[3];
    const float* gb2 = (const float*)d_in[4];
    const float* gw3 = (const float*)d_in[5];
    const float* gb3 = (const float*)d_in[6];
    const float* w0 = (const float*)d_in[7];
    const float* b0 = (const float*)d_in[8];
    const float* w1 = (const float*)d_in[9];
    const float* b1 = (const float*)d_in[10];
    const float* w2 = (const float*)d_in[11];
    const float* b2 = (const float*)d_in[12];
    (void)in_sizes; (void)n_in; (void)out_size; (void)ws_size;

    constexpr int KE0 = NE * DIN + 128;  // 4224 (66 tiles of 64)
    constexpr int KE1 = NE * H0 + 128;   // 8320 (130 tiles of 64)

    // workspace layout (region0 reused by x2b after L0; x1b reused by p2)
    char* ws = (char*)d_ws;
    ushort_t* x0b = (ushort_t*)(ws + 0);                 // 16,777,216
    ushort_t* W0t = (ushort_t*)(ws + 16777216);          //  8,650,752  [1024][4224]
    ushort_t* G1t = (ushort_t*)(ws + 25427968);          //    131,072
    ushort_t* G2t = (ushort_t*)(ws + 25559040);          //     32,768
    ushort_t* h1b = (ushort_t*)(ws + 25591808);          //  4,194,304
    ushort_t* h2b = (ushort_t*)(ws + 29786112);          //  4,194,304
    ushort_t* x2b = (ushort_t*)(ws + 0);                 // 33,554,432 ALIAS of region0
    ushort_t* W1t = (ushort_t*)(ws + 33980416);          // 17,039,360  [1024][8320]
    ushort_t* W2t = (ushort_t*)(ws + 51019776);          //  1,048,576  [64][8192]
    float*    gv  = (float*)(ws + 52068352);             //    524,288
    ushort_t* Gx  = (ushort_t*)(ws + 52592640);          //  4,194,304  [B][128]
    ushort_t* x1b = (ushort_t*)(ws + 56786944);          // 33,554,432
    float*    p2  = (float*)(ws + 56786944);             // ALIAS of x1b (dead after L1)

    // convert + transpose weights/inputs to bf16
    f32_to_bf16_vec<<<dim3((BB * DIN) / (256 * 8)), 256, 0, stream>>>(inputs, x0b);
    transpose_convert<<<dim3((NE * DIN) / 64, H0 / 64), 256, 0, stream>>>(w0, W0t, NE * DIN, H0, KE0);
    transpose_convert<<<dim3((NE * H0) / 64, H1 / 64), 256, 0, stream>>>(w1, W1t, NE * H0, H1, KE1);
    transpose_convert<<<dim3((NE * H1) / 64, DOUT / 64), 256, 0, stream>>>(w2, W2t, NE * H1, DOUT, NE * H1);
    transpose_convert<<<dim3(DIN / 64, GH / 64), 256, 0, stream>>>(gw1, G1t, DIN, GH, DIN);
    transpose_convert<<<dim3(GH / 64, GH / 64), 256, 0, stream>>>(gw2, G2t, GH, GH, GH);
    bias_fill<<<dim3(H0), 128, 0, stream>>>(b0, W0t, H0, NE * DIN, KE0);
    bias_fill<<<dim3(H1), 128, 0, stream>>>(b1, W1t, H1, NE * H0, KE1);

    // gate MLP (BN=64 -> 256 blocks: full-chip on the latency-bound layers)
    moe_gemm<64, 0, 0, false, false><<<dim3(BB / 128, GH / 64), 256, 0, stream>>>(
        x0b, G1t, nullptr, gb1, h1b, BB, GH, DIN, DIN);
    moe_gemm<64, 0, 0, false, false><<<dim3(BB / 128, GH / 64), 256, 0, stream>>>(
        h1b, G2t, nullptr, gb2, h2b, BB, GH, GH, GH);
    gate3_softmax<<<dim3(BB / 256), 256, 0, stream>>>(h2b, gw3, gb3, gv, Gx);

    // expert layers 0,1: A-in-registers 128x128 kernel (gating Horner-folded)
    gemm_areg<DIN / 64, DIN><<<dim3((BB / 128) * (H0 / 128)), 256, 0, stream>>>(
        x0b, Gx, W0t, gv, x1b, H0, KE0);
    gemm_areg<H0 / 64, H0><<<dim3((BB / 128) * (H1 / 128)), 256, 0, stream>>>(
        x1b, Gx, W1t, gv, x2b, H1, KE1);

    // expert layer 2 (N=64): per-expert split-K (z = expert, ungated raw
    // partials; TPE=16 sets A-stride 1024), then gated reduce + bias + tanh
    moe_gemm<64, 16, 2, false, true><<<dim3(BB / 128, DOUT / 64, 8), 256, 0, stream>>>(
        x2b, W2t, nullptr, nullptr, p2, BB, DOUT, NE * H1, H1);
    splitk_reduce8<<<dim3((BB * DOUT) / 256), 256, 0, stream>>>(p2, gv, b2, (float*)d_out);
}

// Round 15
// 483.305 us; speedup vs baseline: 3.5160x; 3.5160x over previous
//
#include <hip/hip_runtime.h>
#include <hip/hip_bf16.h>
#include <cstdint>

#define DI __device__ __forceinline__

typedef unsigned short ushort_t;
using u16x8  = __attribute__((ext_vector_type(8))) unsigned short;
using bf16x8 = __attribute__((ext_vector_type(8))) __bf16;
using f32x4  = __attribute__((ext_vector_type(4))) float;
using f32x16 = __attribute__((ext_vector_type(16))) float;

typedef const __attribute__((address_space(1))) void GVOID;
typedef __attribute__((address_space(3))) void LVOID;

enum { BB = 16384, DIN = 512, H0 = 1024, H1 = 1024, DOUT = 64, NE = 8, GH = 128 };

DI void async_ld16(const void* g, void* l) {
    __builtin_amdgcn_global_load_lds((GVOID*)g, (LVOID*)l, 16, 0, 0);
}

DI unsigned short f2bf(float f) {  // RTNE f32 -> bf16 bits
    union { float f; unsigned u; } v; v.f = f;
    unsigned r = v.u + 0x7FFF + ((v.u >> 16) & 1);
    return (unsigned short)(r >> 16);
}
DI float bf2f(unsigned short u) { return __uint_as_float(((unsigned)u) << 16); }
DI f32x4 zero4() { f32x4 v = {0.f, 0.f, 0.f, 0.f}; return v; }

#define BARRIER() do { __builtin_amdgcn_s_barrier(); asm volatile("" ::: "memory"); } while (0)
#define LGKM0()   asm volatile("s_waitcnt lgkmcnt(0)" ::: "memory")

// ---------------------------------------------------------------------------
// f32 -> bf16 convert (inputs), 8 elems/thread, exact grid
// ---------------------------------------------------------------------------
__global__ void f32_to_bf16_vec(const float* __restrict__ in, ushort_t* __restrict__ out) {
    const int i = (blockIdx.x * 256 + threadIdx.x) * 8;
    const float4 a = *(const float4*)&in[i];
    const float4 b = *(const float4*)&in[i + 4];
    u16x8 o;
    o[0] = f2bf(a.x); o[1] = f2bf(a.y); o[2] = f2bf(a.z); o[3] = f2bf(a.w);
    o[4] = f2bf(b.x); o[5] = f2bf(b.y); o[6] = f2bf(b.z); o[7] = f2bf(b.w);
    *(u16x8*)&out[i] = o;
}

// ---------------------------------------------------------------------------
// W [K][N] f32 -> Wt [N][Kext] bf16 (cols [0,K)), 64x64 tiles via LDS
// ---------------------------------------------------------------------------
__global__ void transpose_convert(const float* __restrict__ W, ushort_t* __restrict__ Wt,
                                  int K, int N, int Kext) {
    __shared__ float t[64][69];
    const int tid = threadIdx.x;
    const int k0 = blockIdx.x * 64, n0 = blockIdx.y * 64;
    for (int rr = tid >> 4; rr < 64; rr += 16) {
        const int c = (tid & 15) * 4;
        const float4 v = *(const float4*)&W[(size_t)(k0 + rr) * N + n0 + c];
        t[rr][c] = v.x; t[rr][c + 1] = v.y; t[rr][c + 2] = v.z; t[rr][c + 3] = v.w;
    }
    __syncthreads();
    for (int nn = tid >> 3; nn < 64; nn += 32) {
        const int k8 = (tid & 7) * 8;
        u16x8 o;
#pragma unroll
        for (int j = 0; j < 8; ++j) o[j] = f2bf(t[k8 + j][nn]);
        *(u16x8*)&Wt[(size_t)(n0 + nn) * Kext + k0 + k8] = o;
    }
}

// ---------------------------------------------------------------------------
// Fill appended bias chunk: Wt[n][K + c] = bias[c][n] for c<8, else 0
// ---------------------------------------------------------------------------
__global__ void bias_fill(const float* __restrict__ bias, ushort_t* __restrict__ Wt,
                          int N, int K, int Kext) {
    const int n = blockIdx.x, c = threadIdx.x;  // 128 threads
    Wt[(size_t)n * Kext + K + c] = (c < 8) ? f2bf(bias[(size_t)c * N + n]) : (ushort_t)0;
}

// ---------------------------------------------------------------------------
// gate layer 3 + softmax: h2 [B,128] bf16 @ gw3 [128,8] f32 + gb3 -> softmax
// writes g [B,8] f32  AND  Gx [B,128] bf16 = (g | zeros)
// ---------------------------------------------------------------------------
__global__ void gate3_softmax(const ushort_t* __restrict__ h2, const float* __restrict__ gw3,
                              const float* __restrict__ gb3, float* __restrict__ g,
                              ushort_t* __restrict__ Gx) {
    __shared__ float w[GH * NE];
    const int tid = threadIdx.x;
    for (int i = tid; i < GH * NE; i += 256) w[i] = gw3[i];
    __syncthreads();
    const int b = blockIdx.x * 256 + tid;
    float lg[NE];
#pragma unroll
    for (int e = 0; e < NE; ++e) lg[e] = gb3[e];
    const ushort_t* row = h2 + (size_t)b * GH;
    for (int h8 = 0; h8 < GH; h8 += 8) {
        const u16x8 v = *(const u16x8*)&row[h8];
#pragma unroll
        for (int j = 0; j < 8; ++j) {
            const float xv = bf2f(v[j]);
#pragma unroll
            for (int e = 0; e < NE; ++e) lg[e] += xv * w[(h8 + j) * NE + e];
        }
    }
    float mx = lg[0];
#pragma unroll
    for (int e = 1; e < NE; ++e) mx = fmaxf(mx, lg[e]);
    float s = 0.f;
#pragma unroll
    for (int e = 0; e < NE; ++e) { lg[e] = __expf(lg[e] - mx); s += lg[e]; }
    const float inv = 1.f / s;
#pragma unroll
    for (int e = 0; e < NE; ++e) g[(size_t)b * NE + e] = lg[e] * inv;
    ushort_t* gxr = Gx + (size_t)b * 128;
    u16x8 o;
#pragma unroll
    for (int e = 0; e < NE; ++e) o[e] = f2bf(lg[e] * inv);
    *(u16x8*)gxr = o;
    u16x8 z = {0, 0, 0, 0, 0, 0, 0, 0};
#pragma unroll
    for (int i = 1; i < 16; ++i) *(u16x8*)(gxr + i * 8) = z;
}

// ---------------------------------------------------------------------------
// 2-PHASE pipelined 256x256 MoE GEMM — r13 skeleton, 32x32x16 MFMA.
//   out = relu( sum_e g_e (X W_e) + sum_e g_e b_e )
// r15 change: mfma_f32_32x32x16_bf16 (2382 TF ubench) replaces 16x16x32
// (2075 TF): per CU per K-64 tile 256 MFMA x 8.07cy = 2066cy vs 2483cy
// (-17% MFMA term), with IDENTICAL LDS read volume (24 b128/wave/tile) and
// the r13 staging/swizzle/barrier skeleton byte-for-byte.
// Fragment layouts (K-doubling rule, verified for 16x16x32 = l&15 / l>>4):
//   A: row = l&31, k = (l>>5)*8 + i  (bf16x8 = 4 VGPR)
//   B: col = l&31, k = (l>>5)*8 + i  (Wt is [N][K] so B-frag = contiguous k)
//   C/D: col = lane&31, row = (reg&3) + 8*(reg>>2) + 4*(lane>>5), reg 0..15
//        [m74/m101-verified]
// LDS read chunk for (kq, hi): (kq*2+hi) ^ (lr&7) -> lanes 0-7 hit 8 distinct
// chunk columns (conflict-free in the b128 8-lane service groups).
// Per wave: 128x64 output = 4ms x 2ns subtiles of 32x32, acc[4][2] f32x16.
//   P0: read B all (8) + A ms0-1 (8); stage A(t+1); bar; prio1; 16 MFMA;
//       prio0; bar  [B(t) reads retired chip-wide]
//   P1: read A ms2-3 (8); stage B(t+2); bar; prio1; 16 MFMA; prio0; fold;
//       vmcnt(4); bar  [tile t+1 resident]
// vmcnt FIFO identical to r10/r13. 512 threads = 8 waves (2M x 4N).
// ---------------------------------------------------------------------------
template <int TPE64, int STRIDEX>
__global__ __launch_bounds__(512, 2) void gemm256x(
    const ushort_t* __restrict__ X,     // [M, STRIDEX] bf16
    const ushort_t* __restrict__ Gx,    // [M, 128] bf16
    const ushort_t* __restrict__ Wt,    // [N, Kext] bf16
    const float* __restrict__ gvec,     // [M, 8] f32
    ushort_t* __restrict__ out,         // [M, N] bf16
    int N, int Kext) {
    constexpr int TE64 = NE * TPE64;    // # expert K-tiles (of 64)
    const int NT = Kext >> 6;           // total K-tiles
    const int tid = threadIdx.x;
    const int wid = tid >> 6, l = tid & 63;
    const int wm = wid >> 2, wn = wid & 3;
    const int lr = l & 31, hi = l >> 5;

    // XCD-aware block decode: 4 N-blocks sharing an A-panel land on one XCD
    const int b = blockIdx.x;
    const int xcd = b & 7, j2 = b >> 3;
    const int by = j2 & 3, bx = xcd + 8 * (j2 >> 2);
    const int bm0 = bx * 256, bn0 = by * 256;

    __shared__ __align__(1024) char lA[2][2][16384];  // [dbuf][half][128x64]
    __shared__ __align__(1024) char lB[2][2][16384];
    __shared__ float rtab[256 * 8];                   // Horner ratios (8 KB)

    // ratio table: r[row][e] = g_e/g_{e+1} (e<7), r[row][7] = g_7
    for (int r = tid; r < 256; r += 512) {
        const float* gr = gvec + (size_t)(bm0 + r) * 8;
        float ge[8];
#pragma unroll
        for (int e = 0; e < 8; ++e) ge[e] = gr[e];
#pragma unroll
        for (int e = 0; e < 7; ++e) rtab[r * 8 + e] = ge[e] / ge[e + 1];
        rtab[r * 8 + 7] = ge[7];
    }

    // staging (unchanged from r13): half-tile = 128x64 bf16 = 2 gload/thread.
    const int srow = (wid << 3) + (l >> 3);              // 0..63
    const int scol = (((l & 7) ^ (srow & 7)) << 3);      // pre-swizzled elems
    auto stA = [&](int t, int h) {
        char* dst = (char*)lA[t & 1][h] + (wid << 10);
        if (t < TE64) {
            const ushort_t* s = X + (size_t)(bm0 + h * 128 + srow) * STRIDEX
                                  + (t & (TPE64 - 1)) * 64 + scol;
            async_ld16(s, dst);
            async_ld16(s + (size_t)64 * STRIDEX, dst + 8192);
        } else {
            const ushort_t* s = Gx + (size_t)(bm0 + h * 128 + srow) * 128
                                   + (t - TE64) * 64 + scol;
            async_ld16(s, dst);
            async_ld16(s + 64 * 128, dst + 8192);
        }
    };
    auto stB = [&](int t, int h) {
        char* dst = (char*)lB[t & 1][h] + (wid << 10);
        const ushort_t* s = Wt + (size_t)(bn0 + h * 128 + srow) * (size_t)Kext
                              + t * 64 + scol;
        async_ld16(s, dst);
        async_ld16(s + (size_t)64 * Kext, dst + 8192);
    };

    // 32x32 read addressing: row byte = lr*128; chunk byte for k-quarter kq =
    // ((kq*2 + hi) ^ (lr&7)) << 4.  (stored chunk c holds global c^(row&7))
    int ck[4];
#pragma unroll
    for (int kq = 0; kq < 4; ++kq) ck[kq] = (((kq * 2 + hi) ^ (lr & 7)) << 4);
    const int aoff = lr * 128;                       // + ms*4096 + ck
    const int boff = ((wn & 1) << 13) + lr * 128;    // + ns*4096 + ck

    f32x16 acc[4][2];
#pragma unroll
    for (int ms = 0; ms < 4; ++ms)
#pragma unroll
        for (int ns = 0; ns < 2; ++ns)
#pragma unroll
            for (int r = 0; r < 16; ++r) acc[ms][ns][r] = 0.f;

    // prologue: tile 0 fully + B(1); wait tile 0 (B(1)'s 4 stay in flight)
    stB(0, 0); stB(0, 1); stA(0, 0); stA(0, 1);
    stB(1, 0); stB(1, 1);
    LGKM0();  // flush rtab ds_writes for cross-wave visibility at barrier
    asm volatile("s_waitcnt vmcnt(4)" ::: "memory");
    BARRIER();

    for (int t = 0; t < NT; ++t) {
        const char* Ah = (const char*)lA[t & 1][wm] + aoff;
        const char* Bh = (const char*)lB[t & 1][wn >> 1] + boff;
        bf16x8 bfr[2][4], af[2][4];

        // ---- P0: B ns0-1 all kq (8) + A ms0-1 all kq (8); stage A(t+1) ----
#pragma unroll
        for (int ns = 0; ns < 2; ++ns)
#pragma unroll
            for (int kq = 0; kq < 4; ++kq)
                bfr[ns][kq] = *(const bf16x8*)(Bh + ns * 4096 + ck[kq]);
#pragma unroll
        for (int ms = 0; ms < 2; ++ms)
#pragma unroll
            for (int kq = 0; kq < 4; ++kq)
                af[ms][kq] = *(const bf16x8*)(Ah + ms * 4096 + ck[kq]);
        if (t + 1 < NT) { stA(t + 1, 0); stA(t + 1, 1); }
        BARRIER();
        __builtin_amdgcn_s_setprio(1);
#pragma unroll
        for (int ms = 0; ms < 2; ++ms)
#pragma unroll
            for (int ns = 0; ns < 2; ++ns)
#pragma unroll
                for (int kq = 0; kq < 4; ++kq)
                    acc[ms][ns] = __builtin_amdgcn_mfma_f32_32x32x16_bf16(
                        af[ms][kq], bfr[ns][kq], acc[ms][ns], 0, 0, 0);
        __builtin_amdgcn_s_setprio(0);
        BARRIER();
        // all B(t) LDS reads retired chip-wide -> lB[t&1] safe to restage

        // ---- P1: A ms2-3 all kq (8); stage B(t+2); 16 MFMA; fold; wait ----
#pragma unroll
        for (int ms = 0; ms < 2; ++ms)
#pragma unroll
            for (int kq = 0; kq < 4; ++kq)
                af[ms][kq] = *(const bf16x8*)(Ah + (ms + 2) * 4096 + ck[kq]);
        if (t + 2 < NT) { stB(t + 2, 0); stB(t + 2, 1); }
        BARRIER();
        __builtin_amdgcn_s_setprio(1);
#pragma unroll
        for (int ms = 0; ms < 2; ++ms)
#pragma unroll
            for (int ns = 0; ns < 2; ++ns)
#pragma unroll
                for (int kq = 0; kq < 4; ++kq)
                    acc[ms + 2][ns] = __builtin_amdgcn_mfma_f32_32x32x16_bf16(
                        af[ms][kq], bfr[ns][kq], acc[ms + 2][ns], 0, 0, 0);
        __builtin_amdgcn_s_setprio(0);

        // Horner gate fold at expert boundary (register-only + rtab reads)
        if (t < TE64 && ((t + 1) & (TPE64 - 1)) == 0) {
            const int e = t / TPE64;
#pragma unroll
            for (int ms = 0; ms < 4; ++ms)
#pragma unroll
                for (int r = 0; r < 16; ++r) {
                    const int rowl = wm * 128 + ms * 32 + (r & 3) + 8 * (r >> 2) + 4 * hi;
                    const float rv = rtab[rowl * 8 + e];
                    acc[ms][0][r] *= rv;
                    acc[ms][1][r] *= rv;
                }
        }
        // end-wait: retire tile t+1; leave B(t+2)'s 4 in flight.
        if (t + 2 < NT) {
            asm volatile("s_waitcnt vmcnt(4)" ::: "memory");
            BARRIER();
        } else if (t + 1 < NT) {
            asm volatile("s_waitcnt vmcnt(0)" ::: "memory");
            BARRIER();
        }
    }

    // ---- epilogue: relu + bf16 store (bias already folded via K-chunk) ----
#pragma unroll
    for (int ms = 0; ms < 4; ++ms)
#pragma unroll
        for (int ns = 0; ns < 2; ++ns)
#pragma unroll
            for (int r = 0; r < 16; ++r) {
                const int row = bm0 + wm * 128 + ms * 32 + (r & 3) + 8 * (r >> 2) + 4 * hi;
                const int col = bn0 + wn * 64 + ns * 32 + lr;
                out[(size_t)row * N + col] = f2bf(fmaxf(acc[ms][ns][r], 0.f));
            }
}

// ---------------------------------------------------------------------------
// Legacy fused (MoE-)GEMM — gate MLP (ungated, BN=64 for 2x grid) and final
// L2 layer (per-expert split-K). ACT: 0=relu, 1=tanh, 2=none (raw partial).
// TPE>0 with GATED=false: TPE only sets the A-stride (xstride = TPE*BK).
// ---------------------------------------------------------------------------
template <int BN, int TPE, int ACT, bool GATED, bool OUTF32>
__global__ __launch_bounds__(256, 2) void moe_gemm(
    const ushort_t* __restrict__ X, const ushort_t* __restrict__ Wt,
    const float* __restrict__ gvec, const float* __restrict__ bias,
    void* __restrict__ outv, int M, int N, int K, int Klen) {
    constexpr int BM = 128, BK = 64;
    constexpr int NF = BN / 32;
    const int tid = threadIdx.x;
    const int wid = tid >> 6, lane = tid & 63;
    const int lr = lane & 15, lk = lane >> 4;
    const int bm0 = blockIdx.x * BM;
    const int bn0 = blockIdx.y * BN;
    const int wm0 = (wid >> 1) * 64;
    const int wn0 = (wid & 1) * (BN / 2);
    const int koff = blockIdx.z * Klen;
    const int te0 = (TPE > 0) ? koff / (TPE * BK) : 0;

    __shared__ short lds_a[BM * BK];
    __shared__ short lds_b[BN * BK];
    __shared__ float lds_g[BM * 8];
    __shared__ float lds_bias[8 * BN];

    if constexpr (GATED) {
        ((f32x4*)lds_g)[tid] = ((const f32x4*)(gvec + (size_t)bm0 * 8))[tid];
        if constexpr (ACT != 2) {
            for (int i = tid; i < 8 * BN; i += 256) {
                const int e = i / BN, n = i - e * BN;
                lds_bias[i] = bias[(size_t)e * N + bn0 + n];
            }
        }
    }

    f32x4 acc_t[4][NF], acc_p[4][NF];
#pragma unroll
    for (int m = 0; m < 4; ++m)
#pragma unroll
        for (int n = 0; n < NF; ++n) { acc_t[m][n] = zero4(); acc_p[m][n] = zero4(); }

    f32x4(&amain)[4][NF] = GATED ? acc_p : acc_t;

    const int xstride = (TPE > 0) ? TPE * BK : K;
    const int NT = Klen / BK;
    for (int kt = 0; kt < NT; ++kt) {
        int kcolA;
        if constexpr (TPE > 0) kcolA = (kt % TPE) * BK; else kcolA = kt * BK;
        {
            const ushort_t* abase = X + (size_t)bm0 * xstride + kcolA;
#pragma unroll
            for (int c = wid; c < (BM * BK * 2) / 1024; c += 4) {
                const int off = c * 1024 + lane * 16;
                const int r = off >> 7, cbyte = off & 127;
                async_ld16((const char*)abase + (size_t)r * (xstride * 2) + cbyte,
                           (char*)lds_a + c * 1024);
            }
            const ushort_t* bbase = Wt + (size_t)bn0 * K + koff + kt * BK;
#pragma unroll
            for (int c = wid; c < (BN * BK * 2) / 1024; c += 4) {
                const int off = c * 1024 + lane * 16;
                const int r = off >> 7, cbyte = off & 127;
                async_ld16((const char*)bbase + (size_t)r * ((size_t)K * 2) + cbyte,
                           (char*)lds_b + c * 1024);
            }
        }
        __syncthreads();

        bf16x8 af[2][4], bfr[2][NF];
#pragma unroll
        for (int k2 = 0; k2 < 2; ++k2) {
#pragma unroll
            for (int m = 0; m < 4; ++m)
                af[k2][m] = *(const bf16x8*)&lds_a[(wm0 + m * 16 + lr) * BK + k2 * 32 + lk * 8];
#pragma unroll
            for (int n = 0; n < NF; ++n)
                bfr[k2][n] = *(const bf16x8*)&lds_b[(wn0 + n * 16 + lr) * BK + k2 * 32 + lk * 8];
        }
#pragma unroll
        for (int m = 0; m < 4; ++m)
#pragma unroll
            for (int n = 0; n < NF; ++n) {
                amain[m][n] = __builtin_amdgcn_mfma_f32_16x16x32_bf16(af[0][m], bfr[0][n], amain[m][n], 0, 0, 0);
                amain[m][n] = __builtin_amdgcn_mfma_f32_16x16x32_bf16(af[1][m], bfr[1][n], amain[m][n], 0, 0, 0);
            }

        if constexpr (TPE > 0 && GATED) {
            if ((kt + 1) % TPE == 0) {
                const int e = te0 + kt / TPE;
#pragma unroll
                for (int m = 0; m < 4; ++m)
#pragma unroll
                    for (int q = 0; q < 4; ++q) {
                        const float gw = lds_g[(wm0 + m * 16 + lk * 4 + q) * 8 + e];
#pragma unroll
                        for (int n = 0; n < NF; ++n) {
                            acc_t[m][n][q] += gw * acc_p[m][n][q];
                            acc_p[m][n][q] = 0.f;
                        }
                    }
            }
        }
        __syncthreads();
    }

#pragma unroll
    for (int m = 0; m < 4; ++m)
#pragma unroll
        for (int n = 0; n < NF; ++n)
#pragma unroll
            for (int q = 0; q < 4; ++q) {
                const int row = wm0 + m * 16 + lk * 4 + q;
                const int col = wn0 + n * 16 + lr;
                float v = acc_t[m][n][q];
                if constexpr (ACT != 2) {
                    if constexpr (GATED) {
                        float bs = 0.f;
#pragma unroll
                        for (int e = 0; e < 8; ++e) bs += lds_g[row * 8 + e] * lds_bias[e * BN + col];
                        v += bs;
                    } else {
                        v += bias[bn0 + col];
                    }
                }
                if constexpr (ACT == 0) v = fmaxf(v, 0.f);
                else if constexpr (ACT == 1) v = tanhf(v);
                const size_t oidx = (size_t)blockIdx.z * M * N + (size_t)(bm0 + row) * N + (bn0 + col);
                if constexpr (OUTF32) ((float*)outv)[oidx] = v;
                else ((ushort_t*)outv)[oidx] = f2bf(v);
            }
}

// ---------------------------------------------------------------------------
// per-expert split-K reduce for L2: out[i] = tanh(sum_e g_e*(part_e[i]+b2_e))
// part layout: [8][B][64] f32
// ---------------------------------------------------------------------------
__global__ void splitk_reduce8(const float* __restrict__ part, const float* __restrict__ g,
                               const float* __restrict__ b2, float* __restrict__ out) {
    __shared__ float bs[8 * 64];
    const int tid = threadIdx.x;
    for (int i = tid; i < 512; i += 256) bs[i] = b2[i];
    __syncthreads();
    const int idx = blockIdx.x * 256 + tid;
    const int bb = idx >> 6, n = idx & 63;
    const float* gr = g + (size_t)bb * 8;
    float v = 0.f;
#pragma unroll
    for (int e = 0; e < 8; ++e)
        v += gr[e] * (part[(size_t)e * BB * 64 + idx] + bs[e * 64 + n]);
    out[idx] = tanhf(v);
}

// ---------------------------------------------------------------------------
extern "C" void kernel_launch(void* const* d_in, const int* in_sizes, int n_in,
                              void* d_out, int out_size, void* d_ws, size_t ws_size,
                              hipStream_t stream) {
    const float* inputs = (const float*)d_in[0];
    const float* gw1 = (const float*)d_in[1];
    const float* gb1 = (const float*)d_in[2];
    const float* gw2 = (const float*)d_in[3];
    const float* gb2 = (const float*)d_in[4];
    const float* gw3 = (const float*)d_in[5];
    const float* gb3 = (const float*)d_in[6];
    const float* w0 = (const float*)d_in[7];
    const float* b0 = (const float*)d_in[8];
    const float* w1 = (const float*)d_in[9];
    const float* b1 = (const float*)d_in[10];
    const float* w2 = (const float*)d_in[11];
    const float* b2 = (const float*)d_in[12];
    (void)in_sizes; (void)n_in; (void)out_size; (void)ws_size;

    constexpr int KE0 = NE * DIN + 128;  // 4224 (66 tiles of 64)
    constexpr int KE1 = NE * H0 + 128;   // 8320 (130 tiles of 64)

    // workspace layout (region0 reused by x2b after L0; x1b reused by p2)
    char* ws = (char*)d_ws;
    ushort_t* x0b = (ushort_t*)(ws + 0);                 // 16,777,216
    ushort_t* W0t = (ushort_t*)(ws + 16777216);          //  8,650,752  [1024][4224]
    ushort_t* G1t = (ushort_t*)(ws + 25427968);          //    131,072
    ushort_t* G2t = (ushort_t*)(ws + 25559040);          //     32,768
    ushort_t* h1b = (ushort_t*)(ws + 25591808);          //  4,194,304
    ushort_t* h2b = (ushort_t*)(ws + 29786112);          //  4,194,304
    ushort_t* x2b = (ushort_t*)(ws + 0);                 // 33,554,432 ALIAS of region0
    ushort_t* W1t = (ushort_t*)(ws + 33980416);          // 17,039,360  [1024][8320]
    ushort_t* W2t = (ushort_t*)(ws + 51019776);          //  1,048,576  [64][8192]
    float*    gv  = (float*)(ws + 52068352);             //    524,288
    ushort_t* Gx  = (ushort_t*)(ws + 52592640);          //  4,194,304  [B][128]
    ushort_t* x1b = (ushort_t*)(ws + 56786944);          // 33,554,432
    float*    p2  = (float*)(ws + 56786944);             // ALIAS of x1b (dead after L1)

    // convert + transpose weights/inputs to bf16
    f32_to_bf16_vec<<<dim3((BB * DIN) / (256 * 8)), 256, 0, stream>>>(inputs, x0b);
    transpose_convert<<<dim3((NE * DIN) / 64, H0 / 64), 256, 0, stream>>>(w0, W0t, NE * DIN, H0, KE0);
    transpose_convert<<<dim3((NE * H0) / 64, H1 / 64), 256, 0, stream>>>(w1, W1t, NE * H0, H1, KE1);
    transpose_convert<<<dim3((NE * H1) / 64, DOUT / 64), 256, 0, stream>>>(w2, W2t, NE * H1, DOUT, NE * H1);
    transpose_convert<<<dim3(DIN / 64, GH / 64), 256, 0, stream>>>(gw1, G1t, DIN, GH, DIN);
    transpose_convert<<<dim3(GH / 64, GH / 64), 256, 0, stream>>>(gw2, G2t, GH, GH, GH);
    bias_fill<<<dim3(H0), 128, 0, stream>>>(b0, W0t, H0, NE * DIN, KE0);
    bias_fill<<<dim3(H1), 128, 0, stream>>>(b1, W1t, H1, NE * H0, KE1);

    // gate MLP (BN=64 -> 256 blocks: full-chip on the latency-bound layers)
    moe_gemm<64, 0, 0, false, false><<<dim3(BB / 128, GH / 64), 256, 0, stream>>>(
        x0b, G1t, nullptr, gb1, h1b, BB, GH, DIN, DIN);
    moe_gemm<64, 0, 0, false, false><<<dim3(BB / 128, GH / 64), 256, 0, stream>>>(
        h1b, G2t, nullptr, gb2, h2b, BB, GH, GH, GH);
    gate3_softmax<<<dim3(BB / 256), 256, 0, stream>>>(h2b, gw3, gb3, gv, Gx);

    // expert layers 0,1: 2-phase 256^2 kernel with 32x32x16 MFMA
    gemm256x<DIN / 64, DIN><<<dim3((BB / 256) * (H0 / 256)), 512, 0, stream>>>(
        x0b, Gx, W0t, gv, x1b, H0, KE0);
    gemm256x<H0 / 64, H0><<<dim3((BB / 256) * (H1 / 256)), 512, 0, stream>>>(
        x1b, Gx, W1t, gv, x2b, H1, KE1);

    // expert layer 2 (N=64): per-expert split-K (z = expert, ungated raw
    // partials; TPE=16 sets A-stride 1024), then gated reduce + bias + tanh
    moe_gemm<64, 16, 2, false, true><<<dim3(BB / 128, DOUT / 64, 8), 256, 0, stream>>>(
        x2b, W2t, nullptr, nullptr, p2, BB, DOUT, NE * H1, H1);
    splitk_reduce8<<<dim3((BB * DOUT) / 256), 256, 0, stream>>>(p2, gv, b2, (float*)d_out);
}

// Round 16
// 431.848 us; speedup vs baseline: 3.9349x; 1.1192x over previous
//
#include <hip/hip_runtime.h>
#include <hip/hip_bf16.h>
#include <cstdint>

#define DI __device__ __forceinline__

typedef unsigned short ushort_t;
using u16x8  = __attribute__((ext_vector_type(8))) unsigned short;
using bf16x8 = __attribute__((ext_vector_type(8))) __bf16;
using f32x4  = __attribute__((ext_vector_type(4))) float;

typedef const __attribute__((address_space(1))) void GVOID;
typedef __attribute__((address_space(3))) void LVOID;

enum { BB = 16384, DIN = 512, H0 = 1024, H1 = 1024, DOUT = 64, NE = 8, GH = 128 };

DI void async_ld16(const void* g, void* l) {
    __builtin_amdgcn_global_load_lds((GVOID*)g, (LVOID*)l, 16, 0, 0);
}

DI unsigned short f2bf(float f) {  // RTNE f32 -> bf16 bits
    union { float f; unsigned u; } v; v.f = f;
    unsigned r = v.u + 0x7FFF + ((v.u >> 16) & 1);
    return (unsigned short)(r >> 16);
}
DI float bf2f(unsigned short u) { return __uint_as_float(((unsigned)u) << 16); }
DI f32x4 zero4() { f32x4 v = {0.f, 0.f, 0.f, 0.f}; return v; }

#define BARRIER() do { __builtin_amdgcn_s_barrier(); asm volatile("" ::: "memory"); } while (0)
#define LGKM0()   asm volatile("s_waitcnt lgkmcnt(0)" ::: "memory")

// ---------------------------------------------------------------------------
// f32 -> bf16 convert (inputs), 8 elems/thread, exact grid
// ---------------------------------------------------------------------------
__global__ void f32_to_bf16_vec(const float* __restrict__ in, ushort_t* __restrict__ out) {
    const int i = (blockIdx.x * 256 + threadIdx.x) * 8;
    const float4 a = *(const float4*)&in[i];
    const float4 b = *(const float4*)&in[i + 4];
    u16x8 o;
    o[0] = f2bf(a.x); o[1] = f2bf(a.y); o[2] = f2bf(a.z); o[3] = f2bf(a.w);
    o[4] = f2bf(b.x); o[5] = f2bf(b.y); o[6] = f2bf(b.z); o[7] = f2bf(b.w);
    *(u16x8*)&out[i] = o;
}

// ---------------------------------------------------------------------------
// W [K][N] f32 -> Wt [N][Kext] bf16 (cols [0,K)), 64x64 tiles via LDS
// ---------------------------------------------------------------------------
__global__ void transpose_convert(const float* __restrict__ W, ushort_t* __restrict__ Wt,
                                  int K, int N, int Kext) {
    __shared__ float t[64][69];
    const int tid = threadIdx.x;
    const int k0 = blockIdx.x * 64, n0 = blockIdx.y * 64;
    for (int rr = tid >> 4; rr < 64; rr += 16) {
        const int c = (tid & 15) * 4;
        const float4 v = *(const float4*)&W[(size_t)(k0 + rr) * N + n0 + c];
        t[rr][c] = v.x; t[rr][c + 1] = v.y; t[rr][c + 2] = v.z; t[rr][c + 3] = v.w;
    }
    __syncthreads();
    for (int nn = tid >> 3; nn < 64; nn += 32) {
        const int k8 = (tid & 7) * 8;
        u16x8 o;
#pragma unroll
        for (int j = 0; j < 8; ++j) o[j] = f2bf(t[k8 + j][nn]);
        *(u16x8*)&Wt[(size_t)(n0 + nn) * Kext + k0 + k8] = o;
    }
}

// ---------------------------------------------------------------------------
// Fill appended bias chunk (64 cols): Wt[n][K + c] = bias[c][n] for c<8 else 0
// ---------------------------------------------------------------------------
__global__ void bias_fill(const float* __restrict__ bias, ushort_t* __restrict__ Wt,
                          int N, int K, int Kext) {
    const int n = blockIdx.x, c = threadIdx.x;  // 64 threads
    Wt[(size_t)n * Kext + K + c] = (c < 8) ? f2bf(bias[(size_t)c * N + n]) : (ushort_t)0;
}

// ---------------------------------------------------------------------------
// gate layer 3 + softmax: h2 [B,128] bf16 @ gw3 [128,8] f32 + gb3 -> softmax
// writes g [B,8] f32  AND  Gx [B,64] bf16 = (g | zeros)
// ---------------------------------------------------------------------------
__global__ void gate3_softmax(const ushort_t* __restrict__ h2, const float* __restrict__ gw3,
                              const float* __restrict__ gb3, float* __restrict__ g,
                              ushort_t* __restrict__ Gx) {
    __shared__ float w[GH * NE];
    const int tid = threadIdx.x;
    for (int i = tid; i < GH * NE; i += 256) w[i] = gw3[i];
    __syncthreads();
    const int b = blockIdx.x * 256 + tid;
    float lg[NE];
#pragma unroll
    for (int e = 0; e < NE; ++e) lg[e] = gb3[e];
    const ushort_t* row = h2 + (size_t)b * GH;
    for (int h8 = 0; h8 < GH; h8 += 8) {
        const u16x8 v = *(const u16x8*)&row[h8];
#pragma unroll
        for (int j = 0; j < 8; ++j) {
            const float xv = bf2f(v[j]);
#pragma unroll
            for (int e = 0; e < NE; ++e) lg[e] += xv * w[(h8 + j) * NE + e];
        }
    }
    float mx = lg[0];
#pragma unroll
    for (int e = 1; e < NE; ++e) mx = fmaxf(mx, lg[e]);
    float s = 0.f;
#pragma unroll
    for (int e = 0; e < NE; ++e) { lg[e] = __expf(lg[e] - mx); s += lg[e]; }
    const float inv = 1.f / s;
#pragma unroll
    for (int e = 0; e < NE; ++e) g[(size_t)b * NE + e] = lg[e] * inv;
    ushort_t* gxr = Gx + (size_t)b * 64;
    u16x8 o;
#pragma unroll
    for (int e = 0; e < NE; ++e) o[e] = f2bf(lg[e] * inv);
    *(u16x8*)gxr = o;
    u16x8 z = {0, 0, 0, 0, 0, 0, 0, 0};
#pragma unroll
    for (int i = 1; i < 8; ++i) *(u16x8*)(gxr + i * 8) = z;
}

// ---------------------------------------------------------------------------
// 2-PHASE pipelined 256x256 MoE GEMM — VERIFIED BEST (r10/r12/r13 skeleton).
//   out = relu( sum_e g_e (X W_e) + sum_e g_e b_e )
//   P0: read A m0-3 k0+k1 (8) + B n0-3 k0+k1 (8); stage A(t+1); bar;
//       prio1; 32 MFMA (compiler-counted lgkm waits); prio0; bar
//       [B(t) reads retired chip-wide -> lB[t&1] free]
//   P1: read A m4-7 k0+k1 (8); stage B(t+2); bar; prio1; 32 MFMA; prio0;
//       fold; vmcnt(4); bar  [tile t+1 resident; A(t) reads retired]
// vmcnt FIFO: enter t with B(t+1)4; P0 +A(t+1)4; P1 +B(t+2)4 -> 12; end
// vmcnt(4) retires tile t+1. vmcnt(0) only at t=NT-2. Works for any NT>=2.
// Pre-MFMA barriers are LOAD-BEARING (r11: removing them = -5 pts MfmaUtil —
// they keep waves phase-aligned so LDS bursts/MFMA clusters interleave).
// 3-bit XOR swizzle: slot (row,c) holds chunk c^(row&7); read chunk byte =
// chunk0 ^ (k2*64), chunk0 = (lk^(lr&7))<<4 (kept OUT of the row base).
// Horner gate fold at expert boundaries; bias folded as ONE appended 64-col
// K-chunk (r16 trim: was 128). 512 threads = 8 waves (2M x 4N); per-wave
// 128x64 output, acc[8][4].
// ---------------------------------------------------------------------------
template <int TPE64, int STRIDEX>
__global__ __launch_bounds__(512, 2) void gemm256p(
    const ushort_t* __restrict__ X,     // [M, STRIDEX] bf16
    const ushort_t* __restrict__ Gx,    // [M, 64] bf16
    const ushort_t* __restrict__ Wt,    // [N, Kext] bf16
    const float* __restrict__ gvec,     // [M, 8] f32
    ushort_t* __restrict__ out,         // [M, N] bf16
    int N, int Kext) {
    constexpr int TE64 = NE * TPE64;    // # expert K-tiles (of 64)
    const int NT = Kext >> 6;           // total K-tiles (TE64 + 1)
    const int tid = threadIdx.x;
    const int wid = tid >> 6, l = tid & 63;
    const int wm = wid >> 2, wn = wid & 3;
    const int lr = l & 15, lk = l >> 4;

    // XCD-aware block decode: 4 N-blocks sharing an A-panel land on one XCD
    const int b = blockIdx.x;
    const int xcd = b & 7, j2 = b >> 3;
    const int by = j2 & 3, bx = xcd + 8 * (j2 >> 2);
    const int bm0 = bx * 256, bn0 = by * 256;

    __shared__ __align__(1024) char lA[2][2][16384];  // [dbuf][half][128x64]
    __shared__ __align__(1024) char lB[2][2][16384];
    __shared__ float rtab[256 * 8];                   // Horner ratios (8 KB)

    // ratio table: r[row][e] = g_e/g_{e+1} (e<7), r[row][7] = g_7
    for (int r = tid; r < 256; r += 512) {
        const float* gr = gvec + (size_t)(bm0 + r) * 8;
        float ge[8];
#pragma unroll
        for (int e = 0; e < 8; ++e) ge[e] = gr[e];
#pragma unroll
        for (int e = 0; e < 7; ++e) rtab[r * 8 + e] = ge[e] / ge[e + 1];
        rtab[r * 8 + 7] = ge[7];
    }

    // staging: half-tile = 128 rows x 64 cols bf16 = 16 KB = 2 gload/thread.
    const int srow = (wid << 3) + (l >> 3);              // 0..63
    const int scol = (((l & 7) ^ (srow & 7)) << 3);      // pre-swizzled elems
    auto stA = [&](int t, int h) {
        char* dst = (char*)lA[t & 1][h] + (wid << 10);
        if (t < TE64) {
            const ushort_t* s = X + (size_t)(bm0 + h * 128 + srow) * STRIDEX
                                  + (t & (TPE64 - 1)) * 64 + scol;
            async_ld16(s, dst);
            async_ld16(s + (size_t)64 * STRIDEX, dst + 8192);
        } else {  // single bias tile: Gx [M,64]
            const ushort_t* s = Gx + (size_t)(bm0 + h * 128 + srow) * 64 + scol;
            async_ld16(s, dst);
            async_ld16(s + 64 * 64, dst + 8192);
        }
    };
    auto stB = [&](int t, int h) {
        char* dst = (char*)lB[t & 1][h] + (wid << 10);
        const ushort_t* s = Wt + (size_t)(bn0 + h * 128 + srow) * (size_t)Kext
                              + t * 64 + scol;
        async_ld16(s, dst);
        async_ld16(s + (size_t)64 * Kext, dst + 8192);
    };

    // swizzled read addressing: row byte = localrow*128 (chunk NOT folded in);
    // chunk byte for k2 = chunk0 ^ (k2*64), chunk0 = (lk ^ (lr&7))<<4.
    const int chunk0 = ((lk ^ (lr & 7)) << 4);
    const int aoff = lr * 128;                       // + m*2048 + chunk
    const int boff = ((wn & 1) << 13) + lr * 128;    // + n*2048 + chunk

    f32x4 acc[8][4];
#pragma unroll
    for (int m = 0; m < 8; ++m)
#pragma unroll
        for (int n = 0; n < 4; ++n) acc[m][n] = zero4();

    // prologue: tile 0 fully + B(1); wait tile 0 (B(1)'s 4 stay in flight)
    stB(0, 0); stB(0, 1); stA(0, 0); stA(0, 1);
    stB(1, 0); stB(1, 1);
    LGKM0();  // flush rtab ds_writes for cross-wave visibility at barrier
    asm volatile("s_waitcnt vmcnt(4)" ::: "memory");
    BARRIER();

    for (int t = 0; t < NT; ++t) {
        const char* Ah = (const char*)lA[t & 1][wm] + aoff;
        const char* Bh = (const char*)lB[t & 1][wn >> 1] + boff;
        bf16x8 a0[4], a1[4], b0[4], b1[4];

        // ---- P0: A m0-3 k0+k1 (8) + B n0-3 k0+k1 (8); stage A(t+1) ----
#pragma unroll
        for (int m = 0; m < 4; ++m) {
            a0[m] = *(const bf16x8*)(Ah + m * 2048 + chunk0);
            a1[m] = *(const bf16x8*)(Ah + m * 2048 + (chunk0 ^ 64));
        }
#pragma unroll
        for (int n = 0; n < 4; ++n) {
            b0[n] = *(const bf16x8*)(Bh + n * 2048 + chunk0);
            b1[n] = *(const bf16x8*)(Bh + n * 2048 + (chunk0 ^ 64));
        }
        if (t + 1 < NT) { stA(t + 1, 0); stA(t + 1, 1); }
        BARRIER();
        __builtin_amdgcn_s_setprio(1);
#pragma unroll
        for (int m = 0; m < 4; ++m)
#pragma unroll
            for (int n = 0; n < 4; ++n) {
                acc[m][n] = __builtin_amdgcn_mfma_f32_16x16x32_bf16(a0[m], b0[n], acc[m][n], 0, 0, 0);
                acc[m][n] = __builtin_amdgcn_mfma_f32_16x16x32_bf16(a1[m], b1[n], acc[m][n], 0, 0, 0);
            }
        __builtin_amdgcn_s_setprio(0);
        BARRIER();
        // all B(t) LDS reads retired chip-wide -> lB[t&1] safe to restage

        // ---- P1: A m4-7 k0+k1 (8); stage B(t+2); 32 MFMA; fold; wait ----
#pragma unroll
        for (int m = 0; m < 4; ++m) {
            a0[m] = *(const bf16x8*)(Ah + (m + 4) * 2048 + chunk0);
            a1[m] = *(const bf16x8*)(Ah + (m + 4) * 2048 + (chunk0 ^ 64));
        }
        if (t + 2 < NT) { stB(t + 2, 0); stB(t + 2, 1); }
        BARRIER();
        __builtin_amdgcn_s_setprio(1);
#pragma unroll
        for (int m = 0; m < 4; ++m)
#pragma unroll
            for (int n = 0; n < 4; ++n) {
                acc[m + 4][n] = __builtin_amdgcn_mfma_f32_16x16x32_bf16(a0[m], b0[n], acc[m + 4][n], 0, 0, 0);
                acc[m + 4][n] = __builtin_amdgcn_mfma_f32_16x16x32_bf16(a1[m], b1[n], acc[m + 4][n], 0, 0, 0);
            }
        __builtin_amdgcn_s_setprio(0);

        // Horner gate fold at expert boundary (register-only + rtab reads)
        if (t < TE64 && ((t + 1) & (TPE64 - 1)) == 0) {
            const int e = t / TPE64;
#pragma unroll
            for (int m = 0; m < 8; ++m)
#pragma unroll
                for (int q = 0; q < 4; ++q) {
                    const float r = rtab[(wm * 128 + m * 16 + lk * 4 + q) * 8 + e];
#pragma unroll
                    for (int n = 0; n < 4; ++n) acc[m][n][q] *= r;
                }
        }
        // end-wait: retire tile t+1 (B from P1(t-1), A from P0(t));
        // leave B(t+2)'s 4 in flight. Queue: [B(t+1)4, A(t+1)4, B(t+2)4].
        if (t + 2 < NT) {
            asm volatile("s_waitcnt vmcnt(4)" ::: "memory");
            BARRIER();
        } else if (t + 1 < NT) {
            asm volatile("s_waitcnt vmcnt(0)" ::: "memory");
            BARRIER();
        }
    }

    // ---- epilogue: relu + bf16 store (bias already folded via K-chunk) ----
#pragma unroll
    for (int m = 0; m < 8; ++m) {
        const int row = bm0 + wm * 128 + m * 16 + lk * 4;
#pragma unroll
        for (int n = 0; n < 4; ++n) {
            const int col = bn0 + wn * 64 + n * 16 + lr;
#pragma unroll
            for (int q = 0; q < 4; ++q) {
                const float v = fmaxf(acc[m][n][q], 0.f);
                out[(size_t)(row + q) * N + col] = f2bf(v);
            }
        }
    }
}

// ---------------------------------------------------------------------------
// Legacy fused (MoE-)GEMM — gate MLP (ungated, BN=64 for 2x grid) and final
// L2 layer (per-expert split-K). ACT: 0=relu, 1=tanh, 2=none (raw partial).
// TPE>0 with GATED=false: TPE only sets the A-stride (xstride = TPE*BK).
// ---------------------------------------------------------------------------
template <int BN, int TPE, int ACT, bool GATED, bool OUTF32>
__global__ __launch_bounds__(256, 2) void moe_gemm(
    const ushort_t* __restrict__ X, const ushort_t* __restrict__ Wt,
    const float* __restrict__ gvec, const float* __restrict__ bias,
    void* __restrict__ outv, int M, int N, int K, int Klen) {
    constexpr int BM = 128, BK = 64;
    constexpr int NF = BN / 32;
    const int tid = threadIdx.x;
    const int wid = tid >> 6, lane = tid & 63;
    const int lr = lane & 15, lk = lane >> 4;
    const int bm0 = blockIdx.x * BM;
    const int bn0 = blockIdx.y * BN;
    const int wm0 = (wid >> 1) * 64;
    const int wn0 = (wid & 1) * (BN / 2);
    const int koff = blockIdx.z * Klen;
    const int te0 = (TPE > 0) ? koff / (TPE * BK) : 0;

    __shared__ short lds_a[BM * BK];
    __shared__ short lds_b[BN * BK];
    __shared__ float lds_g[BM * 8];
    __shared__ float lds_bias[8 * BN];

    if constexpr (GATED) {
        ((f32x4*)lds_g)[tid] = ((const f32x4*)(gvec + (size_t)bm0 * 8))[tid];
        if constexpr (ACT != 2) {
            for (int i = tid; i < 8 * BN; i += 256) {
                const int e = i / BN, n = i - e * BN;
                lds_bias[i] = bias[(size_t)e * N + bn0 + n];
            }
        }
    }

    f32x4 acc_t[4][NF], acc_p[4][NF];
#pragma unroll
    for (int m = 0; m < 4; ++m)
#pragma unroll
        for (int n = 0; n < NF; ++n) { acc_t[m][n] = zero4(); acc_p[m][n] = zero4(); }

    f32x4(&amain)[4][NF] = GATED ? acc_p : acc_t;

    const int xstride = (TPE > 0) ? TPE * BK : K;
    const int NT = Klen / BK;
    for (int kt = 0; kt < NT; ++kt) {
        int kcolA;
        if constexpr (TPE > 0) kcolA = (kt % TPE) * BK; else kcolA = kt * BK;
        {
            const ushort_t* abase = X + (size_t)bm0 * xstride + kcolA;
#pragma unroll
            for (int c = wid; c < (BM * BK * 2) / 1024; c += 4) {
                const int off = c * 1024 + lane * 16;
                const int r = off >> 7, cbyte = off & 127;
                async_ld16((const char*)abase + (size_t)r * (xstride * 2) + cbyte,
                           (char*)lds_a + c * 1024);
            }
            const ushort_t* bbase = Wt + (size_t)bn0 * K + koff + kt * BK;
#pragma unroll
            for (int c = wid; c < (BN * BK * 2) / 1024; c += 4) {
                const int off = c * 1024 + lane * 16;
                const int r = off >> 7, cbyte = off & 127;
                async_ld16((const char*)bbase + (size_t)r * ((size_t)K * 2) + cbyte,
                           (char*)lds_b + c * 1024);
            }
        }
        __syncthreads();

        bf16x8 af[2][4], bfr[2][NF];
#pragma unroll
        for (int k2 = 0; k2 < 2; ++k2) {
#pragma unroll
            for (int m = 0; m < 4; ++m)
                af[k2][m] = *(const bf16x8*)&lds_a[(wm0 + m * 16 + lr) * BK + k2 * 32 + lk * 8];
#pragma unroll
            for (int n = 0; n < NF; ++n)
                bfr[k2][n] = *(const bf16x8*)&lds_b[(wn0 + n * 16 + lr) * BK + k2 * 32 + lk * 8];
        }
#pragma unroll
        for (int m = 0; m < 4; ++m)
#pragma unroll
            for (int n = 0; n < NF; ++n) {
                amain[m][n] = __builtin_amdgcn_mfma_f32_16x16x32_bf16(af[0][m], bfr[0][n], amain[m][n], 0, 0, 0);
                amain[m][n] = __builtin_amdgcn_mfma_f32_16x16x32_bf16(af[1][m], bfr[1][n], amain[m][n], 0, 0, 0);
            }

        if constexpr (TPE > 0 && GATED) {
            if ((kt + 1) % TPE == 0) {
                const int e = te0 + kt / TPE;
#pragma unroll
                for (int m = 0; m < 4; ++m)
#pragma unroll
                    for (int q = 0; q < 4; ++q) {
                        const float gw = lds_g[(wm0 + m * 16 + lk * 4 + q) * 8 + e];
#pragma unroll
                        for (int n = 0; n < NF; ++n) {
                            acc_t[m][n][q] += gw * acc_p[m][n][q];
                            acc_p[m][n][q] = 0.f;
                        }
                    }
            }
        }
        __syncthreads();
    }

#pragma unroll
    for (int m = 0; m < 4; ++m)
#pragma unroll
        for (int n = 0; n < NF; ++n)
#pragma unroll
            for (int q = 0; q < 4; ++q) {
                const int row = wm0 + m * 16 + lk * 4 + q;
                const int col = wn0 + n * 16 + lr;
                float v = acc_t[m][n][q];
                if constexpr (ACT != 2) {
                    if constexpr (GATED) {
                        float bs = 0.f;
#pragma unroll
                        for (int e = 0; e < 8; ++e) bs += lds_g[row * 8 + e] * lds_bias[e * BN + col];
                        v += bs;
                    } else {
                        v += bias[bn0 + col];
                    }
                }
                if constexpr (ACT == 0) v = fmaxf(v, 0.f);
                else if constexpr (ACT == 1) v = tanhf(v);
                const size_t oidx = (size_t)blockIdx.z * M * N + (size_t)(bm0 + row) * N + (bn0 + col);
                if constexpr (OUTF32) ((float*)outv)[oidx] = v;
                else ((ushort_t*)outv)[oidx] = f2bf(v);
            }
}

// ---------------------------------------------------------------------------
// per-expert split-K reduce for L2: out[i] = tanh(sum_e g_e*(part_e[i]+b2_e))
// part layout: [8][B][64] f32
// ---------------------------------------------------------------------------
__global__ void splitk_reduce8(const float* __restrict__ part, const float* __restrict__ g,
                               const float* __restrict__ b2, float* __restrict__ out) {
    __shared__ float bs[8 * 64];
    const int tid = threadIdx.x;
    for (int i = tid; i < 512; i += 256) bs[i] = b2[i];
    __syncthreads();
    const int idx = blockIdx.x * 256 + tid;
    const int bb = idx >> 6, n = idx & 63;
    const float* gr = g + (size_t)bb * 8;
    float v = 0.f;
#pragma unroll
    for (int e = 0; e < 8; ++e)
        v += gr[e] * (part[(size_t)e * BB * 64 + idx] + bs[e * 64 + n]);
    out[idx] = tanhf(v);
}

// ---------------------------------------------------------------------------
extern "C" void kernel_launch(void* const* d_in, const int* in_sizes, int n_in,
                              void* d_out, int out_size, void* d_ws, size_t ws_size,
                              hipStream_t stream) {
    const float* inputs = (const float*)d_in[0];
    const float* gw1 = (const float*)d_in[1];
    const float* gb1 = (const float*)d_in[2];
    const float* gw2 = (const float*)d_in[3];
    const float* gb2 = (const float*)d_in[4];
    const float* gw3 = (const float*)d_in[5];
    const float* gb3 = (const float*)d_in[6];
    const float* w0 = (const float*)d_in[7];
    const float* b0 = (const float*)d_in[8];
    const float* w1 = (const float*)d_in[9];
    const float* b1 = (const float*)d_in[10];
    const float* w2 = (const float*)d_in[11];
    const float* b2 = (const float*)d_in[12];
    (void)in_sizes; (void)n_in; (void)out_size; (void)ws_size;

    constexpr int KE0 = NE * DIN + 64;   // 4160 (65 tiles of 64)
    constexpr int KE1 = NE * H0 + 64;    // 8256 (129 tiles of 64)

    // workspace layout (region0 reused by x2b after L0; x1b reused by p2)
    char* ws = (char*)d_ws;
    ushort_t* x0b = (ushort_t*)(ws + 0);                 // 16,777,216
    ushort_t* W0t = (ushort_t*)(ws + 16777216);          //  8,517,632  [1024][4160]
    ushort_t* G1t = (ushort_t*)(ws + 25427968);          //    131,072
    ushort_t* G2t = (ushort_t*)(ws + 25559040);          //     32,768
    ushort_t* h1b = (ushort_t*)(ws + 25591808);          //  4,194,304
    ushort_t* h2b = (ushort_t*)(ws + 29786112);          //  4,194,304
    ushort_t* x2b = (ushort_t*)(ws + 0);                 // 33,554,432 ALIAS of region0
    ushort_t* W1t = (ushort_t*)(ws + 33980416);          // 16,908,288  [1024][8256]
    ushort_t* W2t = (ushort_t*)(ws + 51019776);          //  1,048,576  [64][8192]
    float*    gv  = (float*)(ws + 52068352);             //    524,288
    ushort_t* Gx  = (ushort_t*)(ws + 52592640);          //  2,097,152  [B][64]
    ushort_t* x1b = (ushort_t*)(ws + 56786944);          // 33,554,432
    float*    p2  = (float*)(ws + 56786944);             // ALIAS of x1b (dead after L1)

    // convert + transpose weights/inputs to bf16
    f32_to_bf16_vec<<<dim3((BB * DIN) / (256 * 8)), 256, 0, stream>>>(inputs, x0b);
    transpose_convert<<<dim3((NE * DIN) / 64, H0 / 64), 256, 0, stream>>>(w0, W0t, NE * DIN, H0, KE0);
    transpose_convert<<<dim3((NE * H0) / 64, H1 / 64), 256, 0, stream>>>(w1, W1t, NE * H0, H1, KE1);
    transpose_convert<<<dim3((NE * H1) / 64, DOUT / 64), 256, 0, stream>>>(w2, W2t, NE * H1, DOUT, NE * H1);
    transpose_convert<<<dim3(DIN / 64, GH / 64), 256, 0, stream>>>(gw1, G1t, DIN, GH, DIN);
    transpose_convert<<<dim3(GH / 64, GH / 64), 256, 0, stream>>>(gw2, G2t, GH, GH, GH);
    bias_fill<<<dim3(H0), 64, 0, stream>>>(b0, W0t, H0, NE * DIN, KE0);
    bias_fill<<<dim3(H1), 64, 0, stream>>>(b1, W1t, H1, NE * H0, KE1);

    // gate MLP (BN=64 -> 256 blocks: full-chip on the latency-bound layers)
    moe_gemm<64, 0, 0, false, false><<<dim3(BB / 128, GH / 64), 256, 0, stream>>>(
        x0b, G1t, nullptr, gb1, h1b, BB, GH, DIN, DIN);
    moe_gemm<64, 0, 0, false, false><<<dim3(BB / 128, GH / 64), 256, 0, stream>>>(
        h1b, G2t, nullptr, gb2, h2b, BB, GH, GH, GH);
    gate3_softmax<<<dim3(BB / 256), 256, 0, stream>>>(h2b, gw3, gb3, gv, Gx);

    // expert layers 0,1: 2-phase 256^2 kernel (gating Horner-folded)
    gemm256p<DIN / 64, DIN><<<dim3((BB / 256) * (H0 / 256)), 512, 0, stream>>>(
        x0b, Gx, W0t, gv, x1b, H0, KE0);
    gemm256p<H0 / 64, H0><<<dim3((BB / 256) * (H1 / 256)), 512, 0, stream>>>(
        x1b, Gx, W1t, gv, x2b, H1, KE1);

    // expert layer 2 (N=64): per-expert split-K (z = expert, ungated raw
    // partials; TPE=16 sets A-stride 1024), then gated reduce + bias + tanh
    moe_gemm<64, 16, 2, false, true><<<dim3(BB / 128, DOUT / 64, 8), 256, 0, stream>>>(
        x2b, W2t, nullptr, nullptr, p2, BB, DOUT, NE * H1, H1);
    splitk_reduce8<<<dim3((BB * DOUT) / 256), 256, 0, stream>>>(p2, gv, b2, (float*)d_out);
}